// Round 11
// baseline (3260.412 us; speedup 1.0000x reference)
//
#include <hip/hip_runtime.h>

#define H 4096
#define STEPS 100
#define IN_DIM_ 512
#define OUT_DIM_ 64
#define NWG 512            // PROVEN cooperative config: 512 wgs x 256 thr
#define TPB 256
#define COLS_PER_WG 8      // exclusive column ownership: 512*8 = 4096
#define NSLOT 10
#define NRING 16           // spike ring depth (max skew is 1 — ample)
#define TBLK 10            // t-blocking for Iin init
#define DECAY_F 0.95122942450071400910f  // float(exp(-1/20))

// ---- workspace layout (bytes) ----
#define OFF_BAR   0                        // [0,8192): full-barrier tree (memset 0)
#define OFF_IIN   8192                     // STEPS*H f32      = 1,638,400 B
#define OFF_PUB   1646592                  // NRING*NWG u64    =    65,536 B
#define OFF_VSUM  1712128                  // H f32            =    16,384 B
#define OFF_RED   1728512                  // 64*64 f32        =    16,384 B
#define OFF_DLY8  1744896                  // H*H u8           = 16,777,216 B
#define WS_NEED_PACK 18522112

// word indices into bar[]
#define BAR_GRP(g)    (1024 + (g) * 16)    // full-barrier tree: 16 groups of 32 wgs
#define BAR_GCNT      1280
#define BAR_FLAG      1296

#define ALOAD(p)      __hip_atomic_load((p),  __ATOMIC_RELAXED, __HIP_MEMORY_SCOPE_AGENT)
#define ASTORE(p,v)   __hip_atomic_store((p), (v), __ATOMIC_RELAXED, __HIP_MEMORY_SCOPE_AGENT)
#define ALOAD64(p)    __hip_atomic_load((p),  __ATOMIC_RELAXED, __HIP_MEMORY_SCOPE_AGENT)
#define ASTORE64(p,v) __hip_atomic_store((p), (v), __ATOMIC_RELAXED, __HIP_MEMORY_SCOPE_AGENT)

__device__ __forceinline__ void wait_ge(unsigned* p, unsigned tgt) {
    while (ALOAD(p) < tgt) __builtin_amdgcn_s_sleep(1);
}

// hierarchical full-grid barrier (monotonic generations) — init/readout only
__device__ __forceinline__ void full_barrier(unsigned* bar, int wg, unsigned gen, int tid) {
    __syncthreads();
    if (tid == 0) {
        __threadfence();                   // release (wbl2 — fine outside the loop)
        unsigned o = atomicAdd(bar + BAR_GRP(wg >> 5), 1u);
        if (o == gen * 32u - 1u) {
            unsigned g = atomicAdd(bar + BAR_GCNT, 1u);
            if (g == gen * 16u - 1u)
                ASTORE(bar + BAR_FLAG, gen);
        }
        wait_ge(bar + BAR_FLAG, gen);
        __threadfence();                   // acquire
    }
    __syncthreads();
}

__global__ __launch_bounds__(TPB, 2)
void triglial_kernel(const float* __restrict__ x,
                     const float* __restrict__ Wi,
                     const float* __restrict__ Wr,
                     const float* __restrict__ rw,
                     const float* __restrict__ rbias,
                     const int*   __restrict__ delays,
                     unsigned char* __restrict__ dly8,
                     int use_pack,
                     unsigned* __restrict__ bar,
                     float* __restrict__ Iin,
                     unsigned long long* __restrict__ pub,   // [NRING][NWG] {tag,bits}
                     float* __restrict__ vsum_g,
                     float* __restrict__ red_part,
                     float* __restrict__ out)
{
    const int wg   = blockIdx.x;
    const int tid  = threadIdx.x;
    const int lane = tid & 63, wave = tid >> 6;
    const int c    = tid & 7;              // col within wg  [0,8)
    const int r    = tid >> 3;             // row-block id   [0,32), 128 rows each
    const int colbase = wg * COLS_PER_WG;
    const int mycol   = colbase + c;

    __shared__ unsigned long long s_spkvec[64];   // full 4096-bit spike vector
    __shared__ float s_acc[NSLOT][TPB];           // future currents, col tid-exclusive
    __shared__ float s_red4[4][8];
    __shared__ float s_red[4][64];

    // per-leader (tid<8) neuron state in registers
    float nv = 0.f, nrate = 0.f, ngamma = 1.f, nvsum = 0.f;

    // ---------------- init ----------------
    #pragma unroll
    for (int s = 0; s < NSLOT; ++s) s_acc[s][tid] = 0.f;
    for (int idx = wg*TPB + tid; idx < NRING*NWG; idx += NWG*TPB)
        ASTORE64(&pub[idx], 0ull);         // tag 0 = invalid
    if (use_pack) {
        for (int idx = wg*TPB + tid; idx < H*H; idx += NWG*TPB)
            dly8[idx] = (unsigned char)(delays[idx] - 1);
    }
    // Iin[t][j] = x[t] . Wi[:,j] — t-blocked (Wi read 10x total, x wave-uniform)
    if (wg < (STEPS / TBLK) * 16) {        // 160 active wgs, one (10t x 256c) tile
        const int t0 = (wg / 16) * TBLK;
        const int j  = (wg % 16) * 256 + tid;
        float acc[TBLK];
        #pragma unroll
        for (int tt = 0; tt < TBLK; ++tt) acc[tt] = 0.f;
        for (int k = 0; k < IN_DIM_; ++k) {
            const float w = Wi[(size_t)k * H + j];
            #pragma unroll
            for (int tt = 0; tt < TBLK; ++tt)
                acc[tt] += x[(t0 + tt) * IN_DIM_ + k] * w;
        }
        #pragma unroll
        for (int tt = 0; tt < TBLK; ++tt) Iin[(t0 + tt) * H + j] = acc[tt];
    }
    full_barrier(bar, wg, 1u, tid);

    // ---- time loop: spike-broadcast dataflow; zero fences, 2 syncs/step ----
    for (int t = 0; t < STEPS; ++t) {
        // leaders prefetch their input current (hidden under the spin below)
        float iin = 0.f;
        if (tid < 8) iin = Iin[t * H + colbase + tid];

        // 1) read + assemble spikes(t-1): 512 coalesced tagged words
        if (t > 0 && tid < 64) {
            unsigned long long* pp = pub + ((t - 1) & (NRING - 1)) * NWG + tid * 8;
            const unsigned want = (unsigned)t;       // tag = step + 1
            unsigned long long u[8];
            #pragma unroll
            for (int k = 0; k < 8; ++k) u[k] = ALOAD64(&pp[k]);
            int spins = 0;
            for (;;) {
                bool stale = false;
                #pragma unroll
                for (int k = 0; k < 8; ++k) {
                    if ((unsigned)(u[k] >> 32) != want) {
                        stale = true;
                        u[k] = ALOAD64(&pp[k]);
                    }
                }
                if (!stale) break;
                if (((++spins) & 1023) == 0) __threadfence();  // stale-line rescue
                __builtin_amdgcn_s_sleep(1);
            }
            unsigned long long bits = 0;
            #pragma unroll
            for (int k = 0; k < 8; ++k)
                bits |= (u[k] & 0xFFull) << (8 * k);
            s_spkvec[tid] = bits;
        }
        __syncthreads();                   // (1) spike vector ready

        // 2) push spikes(t-1) into future slots: rows [r*128, r*128+128) for col c
        if (t > 0) {
            const int tmod = t % 10;
            const int rowb = r << 7;
            unsigned long long m0 = s_spkvec[2*r], m1 = s_spkvec[2*r + 1];
            while (m0 | m1) {
                float wv[16]; int dv[16];
                int cnt = 0;
                #pragma unroll
                for (int b = 0; b < 16; ++b) {
                    if (m0 | m1) {
                        int ii;
                        if (m0) { ii = __ffsll(m0) - 1; m0 &= m0 - 1; }
                        else    { ii = 64 + __ffsll(m1) - 1; m1 &= m1 - 1; }
                        const size_t base = (size_t)(rowb + ii) * H + mycol;
                        wv[b] = Wr[base];                  // plain cached loads
                        dv[b] = use_pack ? (int)dly8[base] : (delays[base] - 1);
                        ++cnt;
                    }
                }
                #pragma unroll
                for (int b = 0; b < 16; ++b) {
                    if (b < cnt) {
                        int slot = tmod + dv[b];           // (t-1 +1+d8) mod 10
                        slot -= (slot >= 10) ? 10 : 0;
                        s_acc[slot][tid] += wv[b];         // tid-exclusive: race-free
                    }
                }
            }
        }

        // 3) export slot t and reduce 32 row-threads per col (in-wave xor tree)
        const int es = t % 10;
        float ex = s_acc[es][tid];
        s_acc[es][tid] = 0.f;              // recycle for step t+10
        ex += __shfl_xor(ex, 8);
        ex += __shfl_xor(ex, 16);
        ex += __shfl_xor(ex, 32);          // every lane: sum of its (lane&7) class
        if (lane < 8) s_red4[wave][lane] = ex;
        __syncthreads();                   // (2) partials ready

        // 4) LIF + publish by the 8 col-leaders (microglia mask==1: 0.99^99 > 0.01)
        if (tid < 8) {
            const float irec = s_red4[0][tid] + s_red4[1][tid]
                             + s_red4[2][tid] + s_red4[3][tid];
            const float itot = (iin + irec) * ngamma;
            float v = nv * DECAY_F + itot;
            const int spk = (v >= 1.0f) ? 1 : 0;
            v = spk ? 0.0f : v;
            nv = v;
            nvsum += v;                    // reference records post-reset v
            nrate = 0.9f * nrate + 0.1f * (float)spk;
            ngamma = fminf(fmaxf(ngamma + 0.01f * (0.1f - nrate), 0.5f), 2.0f);
            const unsigned bits = (unsigned)(__ballot(spk) & 0xFFull);
            if (tid == 0 && t < STEPS - 1)
                ASTORE64(&pub[(t & (NRING - 1)) * NWG + wg],
                         ((unsigned long long)(unsigned)(t + 1) << 32)
                         | (unsigned long long)bits);
        }
        // no third sync: laggards wait at (1); wave-0 reads of s_red4 precede its
        // next-iteration s_spkvec writes in program order; pushes precede (2).
    }

    // ---------------- readout: out = (vsum/STEPS) @ rw + rbias ----------------
    if (tid < 8) vsum_g[colbase + tid] = nvsum;
    full_barrier(bar, wg, 2u, tid);

    if (wg < 64) {                         // wg handles j in [wg*64, wg*64+64)
        const int o  = tid & 63;
        const int jl = tid >> 6;
        float s = 0.f;
        for (int j = wg*64 + jl; j < wg*64 + 64; j += 4)
            s += (vsum_g[j] * (1.0f / (float)STEPS)) * rw[j * OUT_DIM_ + o];
        s_red[jl][o] = s;
        __syncthreads();
        if (tid < 64)
            red_part[wg*64 + tid] =
                s_red[0][tid] + s_red[1][tid] + s_red[2][tid] + s_red[3][tid];
    }
    full_barrier(bar, wg, 3u, tid);

    if (wg == 0 && tid < OUT_DIM_) {
        float s = rbias[tid];
        #pragma unroll 8
        for (int w = 0; w < 64; ++w) s += red_part[w * 64 + tid];
        out[tid] = s;
    }
}

extern "C" void kernel_launch(void* const* d_in, const int* in_sizes, int n_in,
                              void* d_out, int out_size, void* d_ws, size_t ws_size,
                              hipStream_t stream) {
    const float* x      = (const float*)d_in[0];
    const float* Wi     = (const float*)d_in[1];
    const float* Wr     = (const float*)d_in[2];
    const float* rw     = (const float*)d_in[3];
    const float* rb     = (const float*)d_in[4];
    const int*   delays = (const int*)d_in[5];
    float* out = (float*)d_out;

    char* ws = (char*)d_ws;
    unsigned* bar   = (unsigned*)(ws + OFF_BAR);
    float* Iin      = (float*)(ws + OFF_IIN);
    unsigned long long* pub = (unsigned long long*)(ws + OFF_PUB);
    float* vsum_g   = (float*)(ws + OFF_VSUM);
    float* red_part = (float*)(ws + OFF_RED);
    unsigned char* dly8 = (unsigned char*)(ws + OFF_DLY8);
    int use_pack = (ws_size >= (size_t)WS_NEED_PACK) ? 1 : 0;

    // zero the barrier tree (harness poisons ws with 0xAA each launch)
    hipMemsetAsync(ws + OFF_BAR, 0, 8192, stream);

    void* args[] = { (void*)&x, (void*)&Wi, (void*)&Wr, (void*)&rw, (void*)&rb,
                     (void*)&delays, (void*)&dly8, (void*)&use_pack, (void*)&bar,
                     (void*)&Iin, (void*)&pub, (void*)&vsum_g, (void*)&red_part,
                     (void*)&out };
    hipError_t err = hipLaunchCooperativeKernel((void*)triglial_kernel, dim3(NWG),
                                                dim3(TPB), args, 0, stream);
    if (err != hipSuccess) {
        // Fallback: plain launch. Kernel uses only hand-rolled sync; with
        // __launch_bounds__(256,2) and exactly 2 blocks/CU, all 512 blocks
        // are co-resident on the 256-CU device, so the spin protocol is safe.
        triglial_kernel<<<dim3(NWG), dim3(TPB), 0, stream>>>(
            x, Wi, Wr, rw, rb, delays, dly8, use_pack, bar,
            Iin, pub, vsum_g, red_part, out);
    }
}